// Round 1
// baseline (6256.142 us; speedup 1.0000x reference)
//
#include <hip/hip_runtime.h>
#include <cstddef>

// Problem constants (from reference setup_inputs)
#define BB    2048     // batch
#define TT    32       // T_ENC
#define DD    512      // D_IN
#define HH    256      // hidden
#define NCLS  38       // num classes
#define NSTEP 26       // MAXLEN+1
#define XS    560      // padded x row stride (512 context + 38 onehot + 10 zero pad) = 35*16

__device__ __forceinline__ float fast_tanh(float z) {
  float e = __expf(2.f * z);
  return 1.f - 2.f / (e + 1.f);
}
__device__ __forceinline__ float fast_sigmoid(float z) {
  return 1.f / (1.f + __expf(-z));
}

// ---------------------------------------------------------------------------
// prep: pad W_ih [1024,550] -> [1024,560] with zero cols (for float4/BK=16 K-loop)
__global__ __launch_bounds__(256) void pad_wih_kernel(const float* __restrict__ W_ih,
                                                      float* __restrict__ W_ihP) {
  int i = blockIdx.x * 256 + threadIdx.x;
  if (i >= 1024 * XS) return;
  int g = i / XS, k = i - g * XS;
  W_ihP[i] = (k < DD + NCLS) ? W_ih[g * (DD + NCLS) + k] : 0.f;
}

// zero h0 (hiddens slot 0) and c
__global__ __launch_bounds__(256) void init_zero_kernel(float* __restrict__ hid0,
                                                        float* __restrict__ c) {
  int i = blockIdx.x * 256 + threadIdx.x;  // grid covers 2048*256
  hid0[i] = 0.f;
  c[i] = 0.f;
}

// ---------------------------------------------------------------------------
// Generic fp32 GEMM: C[M,N] = A[M,K] @ B[N,K]^T (+ bias[N])
// 64x64 tile, BK=16, 256 threads, 4x4 micro-tile. M%64==0, N%64==0, K%16==0.
__global__ __launch_bounds__(256) void gemm_bias_kernel(
    const float* __restrict__ A, const float* __restrict__ B,
    const float* __restrict__ bias, float* __restrict__ C,
    int M, int N, int K) {
  __shared__ float As[16][68];  // [k][m], pad 68 keeps float4 alignment + bank rotation
  __shared__ float Bs[16][68];  // [k][n]
  const int tid = threadIdx.x;
  const int tx = tid & 15;   // n micro (4 cols)
  const int ty = tid >> 4;   // m micro (4 rows)
  const int m0 = blockIdx.y * 64;
  const int n0 = blockIdx.x * 64;
  float acc[4][4] = {};

  for (int k0 = 0; k0 < K; k0 += 16) {
    int r = tid >> 2;
    int k4 = (tid & 3) * 4;
    float4 av = *(const float4*)(A + (size_t)(m0 + r) * K + k0 + k4);
    As[k4 + 0][r] = av.x; As[k4 + 1][r] = av.y; As[k4 + 2][r] = av.z; As[k4 + 3][r] = av.w;
    float4 bv = *(const float4*)(B + (size_t)(n0 + r) * K + k0 + k4);
    Bs[k4 + 0][r] = bv.x; Bs[k4 + 1][r] = bv.y; Bs[k4 + 2][r] = bv.z; Bs[k4 + 3][r] = bv.w;
    __syncthreads();
#pragma unroll
    for (int kk = 0; kk < 16; ++kk) {
      float4 a4 = *(const float4*)&As[kk][ty * 4];
      float4 b4 = *(const float4*)&Bs[kk][tx * 4];
      float a[4] = {a4.x, a4.y, a4.z, a4.w};
      float b[4] = {b4.x, b4.y, b4.z, b4.w};
#pragma unroll
      for (int i = 0; i < 4; ++i)
#pragma unroll
        for (int j = 0; j < 4; ++j)
          acc[i][j] += a[i] * b[j];
    }
    __syncthreads();
  }

  float bvals[4] = {0.f, 0.f, 0.f, 0.f};
  if (bias) {
#pragma unroll
    for (int j = 0; j < 4; ++j) bvals[j] = bias[n0 + tx * 4 + j];
  }
#pragma unroll
  for (int i = 0; i < 4; ++i) {
    float4 o;
    o.x = acc[i][0] + bvals[0];
    o.y = acc[i][1] + bvals[1];
    o.z = acc[i][2] + bvals[2];
    o.w = acc[i][3] + bvals[3];
    *(float4*)(C + (size_t)(m0 + ty * 4 + i) * N + n0 + tx * 4) = o;
  }
}

// ---------------------------------------------------------------------------
// attention: per step, 8 batch rows per block, 256 threads (4 waves)
// e[i,t] = sum_j W_score[j]*tanh(H_proj[i,t,j]+hp[i,j]); softmax over t;
// x[i,0:512] = sum_t alpha*batch_H; x[i,512+c] = onehot(text[i,s]); pad zeros.
__global__ __launch_bounds__(256) void attn_kernel(
    const float* __restrict__ H_proj, const float* __restrict__ batch_H,
    const float* __restrict__ hp, const float* __restrict__ W_score,
    const int* __restrict__ text, float* __restrict__ x, int s) {
  __shared__ float sh_hp[8][HH];
  __shared__ float sh_ws[HH];
  __shared__ float sh_e[8][TT];
  const int tid = threadIdx.x;
  const int b0 = blockIdx.x * 8;

  for (int idx = tid; idx < 8 * HH / 4; idx += 256)
    ((float4*)&sh_hp[0][0])[idx] = ((const float4*)(hp + (size_t)b0 * HH))[idx];
  if (tid < HH / 4) ((float4*)sh_ws)[tid] = ((const float4*)W_score)[tid];
  __syncthreads();

  // e: each wave handles pairs (i,t), 64-lane dot over j (4 j's per lane)
  const int wv = tid >> 6, ln = tid & 63;
  for (int p = wv; p < 8 * TT; p += 4) {
    int i = p >> 5, t = p & 31;
    float4 hl = *(const float4*)(H_proj + ((size_t)(b0 + i) * TT + t) * HH + ln * 4);
    float4 hpv = *(const float4*)&sh_hp[i][ln * 4];
    float4 wsv = *(const float4*)&sh_ws[ln * 4];
    float v = fast_tanh(hl.x + hpv.x) * wsv.x + fast_tanh(hl.y + hpv.y) * wsv.y +
              fast_tanh(hl.z + hpv.z) * wsv.z + fast_tanh(hl.w + hpv.w) * wsv.w;
#pragma unroll
    for (int m = 32; m >= 1; m >>= 1) v += __shfl_xor(v, m, 64);
    if (ln == 0) sh_e[i][t] = v;
  }
  __syncthreads();

  // softmax over t=32, one thread per (i,t); 32-lane groups align with rows
  {
    int i = tid >> 5, t = tid & 31;
    float e = sh_e[i][t];
    float mx = e;
#pragma unroll
    for (int m = 16; m >= 1; m >>= 1) mx = fmaxf(mx, __shfl_xor(mx, m, 32));
    float pexp = __expf(e - mx);
    float ssum = pexp;
#pragma unroll
    for (int m = 16; m >= 1; m >>= 1) ssum += __shfl_xor(ssum, m, 32);
    sh_e[i][t] = pexp / ssum;  // alpha
  }
  __syncthreads();

  // context: x[i, d] = sum_t alpha[i,t]*batch_H[i,t,d]
  for (int u = tid; u < 8 * (DD / 4); u += 256) {
    int i = u >> 7;
    int d4 = (u & 127) * 4;
    float4 acc = {0.f, 0.f, 0.f, 0.f};
    const float* bh = batch_H + ((size_t)(b0 + i) * TT) * DD + d4;
#pragma unroll
    for (int t = 0; t < TT; ++t) {
      float a = sh_e[i][t];
      float4 h4 = *(const float4*)(bh + (size_t)t * DD);
      acc.x += a * h4.x; acc.y += a * h4.y; acc.z += a * h4.z; acc.w += a * h4.w;
    }
    *(float4*)(x + (size_t)(b0 + i) * XS + d4) = acc;
  }
  // onehot + zero pad (cols 512..559)
  for (int u = tid; u < 8 * (XS - DD); u += 256) {
    int i = u / (XS - DD), cc = u - i * (XS - DD);
    int ch = text[(b0 + i) * NSTEP + s];
    float v = (cc < NCLS && cc == ch) ? 1.f : 0.f;
    x[(size_t)(b0 + i) * XS + DD + cc] = v;
  }
}

// ---------------------------------------------------------------------------
// gates GEMM + LSTM update. Block: 32 batch rows x 64 hidden units x 4 gates.
// gates = x @ W_ihP^T + h @ W_hh^T + b_ih + b_hh; LSTM elementwise; write c, h_out.
__global__ __launch_bounds__(256) void lstm_kernel(
    const float* __restrict__ xin, const float* __restrict__ hin,
    const float* __restrict__ WihP, const float* __restrict__ Whh,
    const float* __restrict__ b_ih, const float* __restrict__ b_hh,
    float* __restrict__ cbuf, float* __restrict__ hout) {
  __shared__ float As[16][34];      // [k][m], m=32 rows
  __shared__ float Bs[4][16][68];   // [gate][k][j], j=64 units
  const int tid = threadIdx.x;
  const int tx = tid & 15;   // j quad: j = tx*4..tx*4+3
  const int ty = tid >> 4;   // m pair: m = ty*2, ty*2+1
  const int j0 = blockIdx.x * 64;
  const int b0 = blockIdx.y * 32;
  float acc[2][4][4] = {};

  // phase 1: A = x rows (K=560), B = W_ihP
  for (int k0 = 0; k0 < XS; k0 += 16) {
    if (tid < 128) {
      int r = tid >> 2, k4 = (tid & 3) * 4;
      float4 av = *(const float4*)(xin + (size_t)(b0 + r) * XS + k0 + k4);
      As[k4 + 0][r] = av.x; As[k4 + 1][r] = av.y; As[k4 + 2][r] = av.z; As[k4 + 3][r] = av.w;
    }
    for (int fi = tid; fi < 1024; fi += 256) {
      int r = fi >> 2, k4 = (fi & 3) * 4;
      int q = r >> 6, j = r & 63;
      float4 bv = *(const float4*)(WihP + (size_t)(q * 256 + j0 + j) * XS + k0 + k4);
      Bs[q][k4 + 0][j] = bv.x; Bs[q][k4 + 1][j] = bv.y; Bs[q][k4 + 2][j] = bv.z; Bs[q][k4 + 3][j] = bv.w;
    }
    __syncthreads();
#pragma unroll
    for (int kk = 0; kk < 16; ++kk) {
      float2 a = *(const float2*)&As[kk][ty * 2];
#pragma unroll
      for (int q = 0; q < 4; ++q) {
        float4 b = *(const float4*)&Bs[q][kk][tx * 4];
        acc[0][q][0] += a.x * b.x; acc[0][q][1] += a.x * b.y;
        acc[0][q][2] += a.x * b.z; acc[0][q][3] += a.x * b.w;
        acc[1][q][0] += a.y * b.x; acc[1][q][1] += a.y * b.y;
        acc[1][q][2] += a.y * b.z; acc[1][q][3] += a.y * b.w;
      }
    }
    __syncthreads();
  }
  // phase 2: A = h rows (K=256), B = W_hh
  for (int k0 = 0; k0 < HH; k0 += 16) {
    if (tid < 128) {
      int r = tid >> 2, k4 = (tid & 3) * 4;
      float4 av = *(const float4*)(hin + (size_t)(b0 + r) * HH + k0 + k4);
      As[k4 + 0][r] = av.x; As[k4 + 1][r] = av.y; As[k4 + 2][r] = av.z; As[k4 + 3][r] = av.w;
    }
    for (int fi = tid; fi < 1024; fi += 256) {
      int r = fi >> 2, k4 = (fi & 3) * 4;
      int q = r >> 6, j = r & 63;
      float4 bv = *(const float4*)(Whh + (size_t)(q * 256 + j0 + j) * HH + k0 + k4);
      Bs[q][k4 + 0][j] = bv.x; Bs[q][k4 + 1][j] = bv.y; Bs[q][k4 + 2][j] = bv.z; Bs[q][k4 + 3][j] = bv.w;
    }
    __syncthreads();
#pragma unroll
    for (int kk = 0; kk < 16; ++kk) {
      float2 a = *(const float2*)&As[kk][ty * 2];
#pragma unroll
      for (int q = 0; q < 4; ++q) {
        float4 b = *(const float4*)&Bs[q][kk][tx * 4];
        acc[0][q][0] += a.x * b.x; acc[0][q][1] += a.x * b.y;
        acc[0][q][2] += a.x * b.z; acc[0][q][3] += a.x * b.w;
        acc[1][q][0] += a.y * b.x; acc[1][q][1] += a.y * b.y;
        acc[1][q][2] += a.y * b.z; acc[1][q][3] += a.y * b.w;
      }
    }
    __syncthreads();
  }

  // epilogue: biases + LSTM cell (gate order i,f,g,o)
#pragma unroll
  for (int mi = 0; mi < 2; ++mi) {
    int b = b0 + ty * 2 + mi;
    int jj0 = j0 + tx * 4;
    float4 cold = *(const float4*)(cbuf + (size_t)b * HH + jj0);
    float cv[4] = {cold.x, cold.y, cold.z, cold.w};
    float cn[4], hn[4];
#pragma unroll
    for (int jj = 0; jj < 4; ++jj) {
      int g = jj0 + jj;
      float iv = fast_sigmoid(acc[mi][0][jj] + b_ih[g] + b_hh[g]);
      float fv = fast_sigmoid(acc[mi][1][jj] + b_ih[256 + g] + b_hh[256 + g]);
      float gv = fast_tanh(acc[mi][2][jj] + b_ih[512 + g] + b_hh[512 + g]);
      float ov = fast_sigmoid(acc[mi][3][jj] + b_ih[768 + g] + b_hh[768 + g]);
      float cc = fv * cv[jj] + iv * gv;
      cn[jj] = cc;
      hn[jj] = ov * fast_tanh(cc);
    }
    float4 co = {cn[0], cn[1], cn[2], cn[3]};
    float4 ho = {hn[0], hn[1], hn[2], hn[3]};
    *(float4*)(cbuf + (size_t)b * HH + jj0) = co;
    *(float4*)(hout + (size_t)b * HH + jj0) = ho;
  }
}

// ---------------------------------------------------------------------------
// probs: out[b,s,c] = W_gen[c,:] . hiddens[s+1][b,:] + b_gen[c]
// hid_all = hiddens slots 1..26 as [26][2048][256] (row r = s*2048+b)
__global__ __launch_bounds__(256) void probs_kernel(
    const float* __restrict__ hid_all, const float* __restrict__ W_gen,
    const float* __restrict__ b_gen, float* __restrict__ out) {
  __shared__ float sh[16][HH];
  const int tid = threadIdx.x;
  const int r0 = blockIdx.x * 16;
  for (int u = tid; u < 16 * (HH / 4); u += 256) {
    int rr = u >> 6, c4 = (u & 63) * 4;
    *(float4*)&sh[rr][c4] = *(const float4*)(hid_all + (size_t)(r0 + rr) * HH + c4);
  }
  __syncthreads();
  for (int oi = tid; oi < 16 * NCLS; oi += 256) {
    int rr = oi / NCLS, cls = oi - rr * NCLS;
    const float* wg = W_gen + (size_t)cls * HH;
    float acc = 0.f;
#pragma unroll
    for (int k4 = 0; k4 < HH; k4 += 4) {
      float4 h4 = *(const float4*)&sh[rr][k4];
      float4 w4 = *(const float4*)(wg + k4);
      acc += h4.x * w4.x + h4.y * w4.y + h4.z * w4.z + h4.w * w4.w;
    }
    int r = r0 + rr;
    int s = r >> 11;         // r / 2048
    int b = r & 2047;
    out[((size_t)b * NSTEP + s) * NCLS + cls] = acc + b_gen[cls];
  }
}

// ---------------------------------------------------------------------------
extern "C" void kernel_launch(void* const* d_in, const int* in_sizes, int n_in,
                              void* d_out, int out_size, void* d_ws, size_t ws_size,
                              hipStream_t stream) {
  const float* batch_H = (const float*)d_in[0];
  const int*   text    = (const int*)d_in[1];
  const float* W_i2h   = (const float*)d_in[2];
  const float* W_h2h   = (const float*)d_in[3];
  const float* b_h2h   = (const float*)d_in[4];
  const float* W_score = (const float*)d_in[5];
  const float* W_ih    = (const float*)d_in[6];
  const float* b_ih    = (const float*)d_in[7];
  const float* W_hh    = (const float*)d_in[8];
  const float* b_hh    = (const float*)d_in[9];
  const float* W_gen   = (const float*)d_in[10];
  const float* b_gen   = (const float*)d_in[11];
  float* out = (float*)d_out;

  // workspace layout (floats): total ~33.7M floats = ~129 MiB
  float* ws      = (float*)d_ws;
  float* H_proj  = ws;                                   // 65536*256
  float* hiddens = H_proj + (size_t)65536 * 256;         // 27*2048*256 (slot 0 = h0 zeros)
  float* cbuf    = hiddens + (size_t)27 * 2048 * 256;    // 2048*256
  float* hpbuf   = cbuf + (size_t)2048 * 256;            // 2048*256
  float* xbuf    = hpbuf + (size_t)2048 * 256;           // 2048*560
  float* wihp    = xbuf + (size_t)2048 * XS;             // 1024*560

  pad_wih_kernel<<<(1024 * XS + 255) / 256, 256, 0, stream>>>(W_ih, wihp);
  init_zero_kernel<<<2048, 256, 0, stream>>>(hiddens, cbuf);

  // H_proj = batch_H @ W_i2h^T  (M=65536, N=256, K=512)
  gemm_bias_kernel<<<dim3(4, 1024), 256, 0, stream>>>(batch_H, W_i2h, nullptr, H_proj,
                                                      65536, 256, 512);

  for (int s = 0; s < NSTEP; ++s) {
    const float* h_s = hiddens + (size_t)s * 2048 * 256;
    float* h_next    = hiddens + (size_t)(s + 1) * 2048 * 256;
    // hp = h_s @ W_h2h^T + b_h2h  (M=2048, N=256, K=256)
    gemm_bias_kernel<<<dim3(4, 32), 256, 0, stream>>>(h_s, W_h2h, b_h2h, hpbuf,
                                                      2048, 256, 256);
    attn_kernel<<<256, 256, 0, stream>>>(H_proj, batch_H, hpbuf, W_score, text, xbuf, s);
    lstm_kernel<<<dim3(4, 64), 256, 0, stream>>>(xbuf, h_s, wihp, W_hh, b_ih, b_hh,
                                                 cbuf, h_next);
  }

  probs_kernel<<<3328, 256, 0, stream>>>(hiddens + (size_t)2048 * 256, W_gen, b_gen, out);
}

// Round 2
// 4396.196 us; speedup vs baseline: 1.4231x; 1.4231x over previous
//
#include <hip/hip_runtime.h>
#include <cstddef>

// Problem constants
#define TT    32       // T_ENC
#define DD    512      // D_IN
#define HH    256      // hidden
#define NCLS  38       // classes
#define NSTEP 26       // MAXLEN+1
#define KX    576      // padded x-part K (512 ctx + 38 onehot + 26 pad) = 18*32
#define KTOT  832      // KX + HH
#define NKC   26       // K chunks of 32 for gates GEMM
#define XCH   34       // XSW chunk count: 18 x-chunks + 8 h(even) + 8 h(odd)

typedef float f32x4 __attribute__((ext_vector_type(4)));
typedef short bf16x8 __attribute__((ext_vector_type(8)));

__device__ __forceinline__ float fast_tanh(float z) {
  float e = __expf(2.f * z);
  return 1.f - 2.f / (e + 1.f);
}
__device__ __forceinline__ float fast_sigmoid(float z) {
  return 1.f / (1.f + __expf(-z));
}
__device__ __forceinline__ float bf2f(unsigned short s) {
  union { unsigned int u; float f; } v; v.u = ((unsigned int)s) << 16; return v.f;
}
__device__ __forceinline__ unsigned short f2bf(float f) {  // RNE
  union { float ff; unsigned int u; } v; v.ff = f;
  unsigned int r = v.u + 0x7FFFu + ((v.u >> 16) & 1u);
  return (unsigned short)(r >> 16);
}
__device__ __forceinline__ unsigned int pk(unsigned short a, unsigned short b) {
  return (unsigned int)a | ((unsigned int)b << 16);
}

// ---------------------------------------------------------------------------
// batch_H fp32 -> bf16 row-major (33,554,432 elems; 8 per thread; grid 16384)
__global__ __launch_bounds__(256) void cvt_bh_kernel(const float* __restrict__ src,
                                                     unsigned short* __restrict__ dst) {
  int t = blockIdx.x * 256 + threadIdx.x;
  const float4* s4 = (const float4*)src + (size_t)t * 2;
  float4 a = s4[0], b = s4[1];
  uint4 o;
  o.x = pk(f2bf(a.x), f2bf(a.y));
  o.y = pk(f2bf(a.z), f2bf(a.w));
  o.z = pk(f2bf(b.x), f2bf(b.y));
  o.w = pk(f2bf(b.z), f2bf(b.w));
  ((uint4*)dst)[t] = o;
}

// gates weights: [W_ihP(576) | W_hh(256)] bf16, gate-interleaved cols, MFMA-B swizzled.
// col = nt*16 + (lane&15); gate=(col>>6)&3; j_global=(col>>8)*64+(col&63); orig=gate*256+j.
__global__ __launch_bounds__(256) void prep_wg_kernel(const float* __restrict__ W_ih,
                                                      const float* __restrict__ W_hh,
                                                      unsigned short* __restrict__ Wg) {
  int flat = blockIdx.x * 256 + threadIdx.x;   // 64*NKC*64 = 106496
  if (flat >= 64 * NKC * 64) return;
  int l = flat & 63, ntkc = flat >> 6;
  int nt = ntkc / NKC, kc = ntkc - nt * NKC;
  int col = nt * 16 + (l & 15);
  int gate = (col >> 6) & 3;
  int jg = (col >> 8) * 64 + (col & 63);
  int orig = gate * 256 + jg;
  int kbase = kc * 32 + (l >> 4) * 8;
  unsigned short e[8];
#pragma unroll
  for (int j = 0; j < 8; ++j) {
    int k = kbase + j;
    float v;
    if (k < DD + NCLS)      v = W_ih[orig * (DD + NCLS) + k];
    else if (k < KX)        v = 0.f;
    else                    v = W_hh[orig * HH + (k - KX)];
    e[j] = f2bf(v);
  }
  uint4 o = {pk(e[0], e[1]), pk(e[2], e[3]), pk(e[4], e[5]), pk(e[6], e[7])};
  ((uint4*)Wg)[flat] = o;
}

// W_i2h [256][512] -> bf16 MFMA-B swizzled [nt(16)][kc(16)][lane][8]
__global__ __launch_bounds__(256) void prep_wi_kernel(const float* __restrict__ W_i2h,
                                                      unsigned short* __restrict__ Wi) {
  int flat = blockIdx.x * 256 + threadIdx.x;   // 16*16*64 = 16384
  int l = flat & 63, ntkc = flat >> 6;
  int nt = ntkc >> 4, kc = ntkc & 15;
  int n = nt * 16 + (l & 15);
  int kbase = kc * 32 + (l >> 4) * 8;
  unsigned short e[8];
#pragma unroll
  for (int j = 0; j < 8; ++j) e[j] = f2bf(W_i2h[(size_t)n * DD + kbase + j]);
  uint4 o = {pk(e[0], e[1]), pk(e[2], e[3]), pk(e[4], e[5]), pk(e[6], e[7])};
  ((uint4*)Wi)[flat] = o;
}

// W_h2h transpose (fp32) + combined bias bc = b_ih + b_hh
__global__ __launch_bounds__(256) void prep_wt_bc_kernel(const float* __restrict__ W_h2h,
                                                         const float* __restrict__ b_ih,
                                                         const float* __restrict__ b_hh,
                                                         float* __restrict__ WT,
                                                         float* __restrict__ bc) {
  int flat = blockIdx.x * 256 + threadIdx.x;   // 65536
  int k = flat >> 8, c = flat & 255;
  WT[k * 256 + c] = W_h2h[c * 256 + k];
  if (flat < 1024) bc[flat] = b_ih[flat] + b_hh[flat];
}

// zero h0 (hiddens slot0), cbuf, XSW h-even chunks (18..25)
__global__ __launch_bounds__(256) void init_zero_kernel(float* __restrict__ hid0,
                                                        float* __restrict__ cbuf,
                                                        unsigned short* __restrict__ XSW) {
  int flat = blockIdx.x * 256 + threadIdx.x;   // 327680
  float4 z = {0.f, 0.f, 0.f, 0.f};
  if (flat < 131072) {
    ((float4*)hid0)[flat] = z;
  } else if (flat < 262144) {
    ((float4*)cbuf)[flat - 131072] = z;
  } else if (flat < 327680) {
    int j = flat - 262144;            // 128 mt * 8 kc * 64 lanes
    int mt = j >> 9, rem = j & 511;
    int kc = 18 + (rem >> 6), lane = rem & 63;
    uint4 zz = {0u, 0u, 0u, 0u};
    ((uint4*)XSW)[((size_t)mt * XCH + kc) * 64 + lane] = zz;
  }
}

// ---------------------------------------------------------------------------
// H_proj = batch_H(bf16 row-major) @ W_i2h^T -> bf16 [65536][256]
// grid 512 blocks * 128 rows; 4 waves row-split (32 rows, all 256 cols).
__global__ __launch_bounds__(256) void hproj_mfma_kernel(const unsigned short* __restrict__ Abf,
                                                         const unsigned short* __restrict__ Wi,
                                                         unsigned short* __restrict__ Hbf) {
  const int tid = threadIdx.x;
  const int w = tid >> 6, l = tid & 63;
  const int li = l & 15, qd = l >> 4;
  const int m0 = blockIdx.x * 128 + w * 32;
  f32x4 acc[2][16];
#pragma unroll
  for (int a = 0; a < 2; ++a)
#pragma unroll
    for (int b = 0; b < 16; ++b) acc[a][b] = (f32x4){0.f, 0.f, 0.f, 0.f};
  const bf16x8* Wi8 = (const bf16x8*)Wi;
  for (int kc = 0; kc < 16; ++kc) {
    bf16x8 a0 = *(const bf16x8*)(Abf + (size_t)(m0 + li) * DD + kc * 32 + qd * 8);
    bf16x8 a1 = *(const bf16x8*)(Abf + (size_t)(m0 + 16 + li) * DD + kc * 32 + qd * 8);
#pragma unroll
    for (int nt = 0; nt < 16; ++nt) {
      bf16x8 b = Wi8[(nt * 16 + kc) * 64 + l];
      acc[0][nt] = __builtin_amdgcn_mfma_f32_16x16x32_bf16(a0, b, acc[0][nt], 0, 0, 0);
      acc[1][nt] = __builtin_amdgcn_mfma_f32_16x16x32_bf16(a1, b, acc[1][nt], 0, 0, 0);
    }
  }
#pragma unroll
  for (int mi = 0; mi < 2; ++mi)
#pragma unroll
    for (int nt = 0; nt < 16; ++nt)
#pragma unroll
      for (int r = 0; r < 4; ++r) {
        int row = m0 + mi * 16 + qd * 4 + r;
        Hbf[(size_t)row * HH + nt * 16 + li] = f2bf(acc[mi][nt][r]);
      }
}

// ---------------------------------------------------------------------------
// fused per-step: hp GEMV + additive attention + context; writes XSW x-part
// (chunks 0..17) in MFMA-A swizzled bf16. 256 blocks * 8 batch rows.
__global__ __launch_bounds__(256) void attn_fused_kernel(
    const unsigned short* __restrict__ Hbf, const unsigned short* __restrict__ bHbf,
    const float* __restrict__ h_s, const float* __restrict__ WT,
    const float* __restrict__ b_h2h, const float* __restrict__ W_score,
    const int* __restrict__ text, unsigned short* __restrict__ XSW, int s) {
  __shared__ float sh_h[8][HH];
  __shared__ float sh_hp[8][HH];
  __shared__ float sh_ws[HH];
  __shared__ float sh_e[8][TT];
  const int tid = threadIdx.x;
  const int b0 = blockIdx.x * 8;

  for (int u = tid; u < 8 * HH / 4; u += 256)
    ((float4*)&sh_h[0][0])[u] = ((const float4*)(h_s + (size_t)b0 * HH))[u];
  if (tid < HH / 4) ((float4*)sh_ws)[tid] = ((const float4*)W_score)[tid];
  __syncthreads();

  // hp[i][c] = sum_k h[i][k] * W_h2h[c][k] + b_h2h[c]  (WT is [k][c])
  {
    int i = tid >> 5, c8 = (tid & 31) * 8;
    float acc[8] = {0.f, 0.f, 0.f, 0.f, 0.f, 0.f, 0.f, 0.f};
#pragma unroll 4
    for (int k = 0; k < HH; ++k) {
      float a = sh_h[i][k];
      float4 w0 = *(const float4*)(WT + k * 256 + c8);
      float4 w1 = *(const float4*)(WT + k * 256 + c8 + 4);
      acc[0] += a * w0.x; acc[1] += a * w0.y; acc[2] += a * w0.z; acc[3] += a * w0.w;
      acc[4] += a * w1.x; acc[5] += a * w1.y; acc[6] += a * w1.z; acc[7] += a * w1.w;
    }
    float4 bb0 = *(const float4*)(b_h2h + c8);
    float4 bb1 = *(const float4*)(b_h2h + c8 + 4);
    sh_hp[i][c8 + 0] = acc[0] + bb0.x; sh_hp[i][c8 + 1] = acc[1] + bb0.y;
    sh_hp[i][c8 + 2] = acc[2] + bb0.z; sh_hp[i][c8 + 3] = acc[3] + bb0.w;
    sh_hp[i][c8 + 4] = acc[4] + bb1.x; sh_hp[i][c8 + 5] = acc[5] + bb1.y;
    sh_hp[i][c8 + 6] = acc[6] + bb1.z; sh_hp[i][c8 + 7] = acc[7] + bb1.w;
  }
  __syncthreads();

  // e[i][t] = sum_j Wscore[j]*tanh(H_proj[i,t,j] + hp[i,j])
  const int wv = tid >> 6, ln = tid & 63;
  for (int p = wv; p < 8 * TT; p += 4) {
    int i = p >> 5, t = p & 31;
    ushort4 hv = *(const ushort4*)(Hbf + ((size_t)(b0 + i) * TT + t) * HH + ln * 4);
    float4 hpv = *(const float4*)&sh_hp[i][ln * 4];
    float4 wsv = *(const float4*)&sh_ws[ln * 4];
    float v = fast_tanh(bf2f(hv.x) + hpv.x) * wsv.x + fast_tanh(bf2f(hv.y) + hpv.y) * wsv.y +
              fast_tanh(bf2f(hv.z) + hpv.z) * wsv.z + fast_tanh(bf2f(hv.w) + hpv.w) * wsv.w;
#pragma unroll
    for (int m = 32; m >= 1; m >>= 1) v += __shfl_xor(v, m, 64);
    if (ln == 0) sh_e[i][t] = v;
  }
  __syncthreads();

  // softmax over t (32-lane groups = one row)
  {
    int i = tid >> 5, t = tid & 31;
    float e = sh_e[i][t];
    float mx = e;
#pragma unroll
    for (int m = 16; m >= 1; m >>= 1) mx = fmaxf(mx, __shfl_xor(mx, m, 32));
    float pexp = __expf(e - mx);
    float ssum = pexp;
#pragma unroll
    for (int m = 16; m >= 1; m >>= 1) ssum += __shfl_xor(ssum, m, 32);
    sh_e[i][t] = pexp / ssum;
  }
  __syncthreads();

  // context -> XSW chunks 0..15 (swizzled bf16)
  for (int u = tid; u < 512; u += 256) {
    int i = u >> 6, d0 = (u & 63) * 8;
    int row = b0 + i;
    float acc[8] = {0.f, 0.f, 0.f, 0.f, 0.f, 0.f, 0.f, 0.f};
    const unsigned short* bh = bHbf + (size_t)row * TT * DD + d0;
#pragma unroll
    for (int t = 0; t < TT; ++t) {
      float a = sh_e[i][t];
      uint4 hv = *(const uint4*)(bh + (size_t)t * DD);
      acc[0] += a * bf2f((unsigned short)(hv.x & 0xFFFF));
      acc[1] += a * bf2f((unsigned short)(hv.x >> 16));
      acc[2] += a * bf2f((unsigned short)(hv.y & 0xFFFF));
      acc[3] += a * bf2f((unsigned short)(hv.y >> 16));
      acc[4] += a * bf2f((unsigned short)(hv.z & 0xFFFF));
      acc[5] += a * bf2f((unsigned short)(hv.z >> 16));
      acc[6] += a * bf2f((unsigned short)(hv.w & 0xFFFF));
      acc[7] += a * bf2f((unsigned short)(hv.w >> 16));
    }
    uint4 o = {pk(f2bf(acc[0]), f2bf(acc[1])), pk(f2bf(acc[2]), f2bf(acc[3])),
               pk(f2bf(acc[4]), f2bf(acc[5])), pk(f2bf(acc[6]), f2bf(acc[7]))};
    int lane_t = ((d0 & 31) >> 3) * 16 + (row & 15);
    ((uint4*)XSW)[((size_t)(row >> 4) * XCH + (d0 >> 5)) * 64 + lane_t] = o;
  }
  // onehot + zero pad -> XSW chunks 16..17
  if (tid < 64) {
    int i = tid >> 3, k0 = DD + (tid & 7) * 8;
    int row = b0 + i;
    int ch = text[row * NSTEP + s];
    unsigned short e8[8];
#pragma unroll
    for (int j = 0; j < 8; ++j) e8[j] = (k0 + j - DD == ch) ? (unsigned short)0x3F80 : (unsigned short)0;
    uint4 o = {pk(e8[0], e8[1]), pk(e8[2], e8[3]), pk(e8[4], e8[5]), pk(e8[6], e8[7])};
    int lane_t = ((k0 & 31) >> 3) * 16 + (row & 15);
    ((uint4*)XSW)[((size_t)(row >> 4) * XCH + (k0 >> 5)) * 64 + lane_t] = o;
  }
}

// ---------------------------------------------------------------------------
// gates = [x|h] @ Wg^T (bf16 MFMA) + LSTM cell. grid (4 col-groups, 16 row-groups);
// 4 waves row-split (32 rows, 256 cols = 64 units x 4 gates).
__global__ __launch_bounds__(256) void lstm_mfma_kernel(
    const unsigned short* __restrict__ XSW, const unsigned short* __restrict__ Wg,
    const float* __restrict__ bc, float* __restrict__ cbuf,
    float* __restrict__ hnext, unsigned short* __restrict__ XSWw,
    int hb_r, int hb_w) {
  const int tid = threadIdx.x;
  const int w = tid >> 6, l = tid & 63;
  const int li = l & 15, qd = l >> 4;
  const int cg = blockIdx.x;
  const int m0 = blockIdx.y * 128 + w * 32;
  const int mt0 = m0 >> 4;
  f32x4 acc[2][16];
#pragma unroll
  for (int a = 0; a < 2; ++a)
#pragma unroll
    for (int b = 0; b < 16; ++b) acc[a][b] = (f32x4){0.f, 0.f, 0.f, 0.f};
  const bf16x8* X8 = (const bf16x8*)XSW;
  const bf16x8* W8 = (const bf16x8*)Wg;
  for (int kc = 0; kc < NKC; ++kc) {
    int skc = (kc < 18) ? kc : (hb_r + (kc - 18));
    bf16x8 a0 = X8[((size_t)mt0 * XCH + skc) * 64 + l];
    bf16x8 a1 = X8[((size_t)(mt0 + 1) * XCH + skc) * 64 + l];
#pragma unroll
    for (int nt = 0; nt < 16; ++nt) {
      bf16x8 b = W8[((size_t)(cg * 16 + nt) * NKC + kc) * 64 + l];
      acc[0][nt] = __builtin_amdgcn_mfma_f32_16x16x32_bf16(a0, b, acc[0][nt], 0, 0, 0);
      acc[1][nt] = __builtin_amdgcn_mfma_f32_16x16x32_bf16(a1, b, acc[1][nt], 0, 0, 0);
    }
  }
  float bcv[4][4];
#pragma unroll
  for (int g = 0; g < 4; ++g)
#pragma unroll
    for (int jj = 0; jj < 4; ++jj) bcv[g][jj] = bc[g * 256 + cg * 64 + jj * 16 + li];
#pragma unroll
  for (int mi = 0; mi < 2; ++mi)
#pragma unroll
    for (int r = 0; r < 4; ++r) {
      int row = m0 + mi * 16 + qd * 4 + r;
#pragma unroll
      for (int jj = 0; jj < 4; ++jj) {
        int jg = cg * 64 + jj * 16 + li;
        float iv = fast_sigmoid(acc[mi][jj][r]      + bcv[0][jj]);
        float fv = fast_sigmoid(acc[mi][4 + jj][r]  + bcv[1][jj]);
        float gv = fast_tanh   (acc[mi][8 + jj][r]  + bcv[2][jj]);
        float ov = fast_sigmoid(acc[mi][12 + jj][r] + bcv[3][jj]);
        float cold = cbuf[(size_t)row * HH + jg];
        float cn = fv * cold + iv * gv;
        float hn = ov * fast_tanh(cn);
        cbuf[(size_t)row * HH + jg] = cn;
        hnext[(size_t)row * HH + jg] = hn;
        int kcx = hb_w + (jg >> 5);
        int k2 = jg & 31;
        XSWw[((size_t)(row >> 4) * XCH + kcx) * 512 + ((k2 >> 3) * 16 + (row & 15)) * 8 + (k2 & 7)] = f2bf(hn);
      }
    }
}

// ---------------------------------------------------------------------------
// probs: out[b,s,c] = hiddens[s+1][b] . W_gen[c] + b_gen[c]  (fp32)
__global__ __launch_bounds__(256) void probs_kernel(
    const float* __restrict__ hid_all, const float* __restrict__ W_gen,
    const float* __restrict__ b_gen, float* __restrict__ out) {
  __shared__ float sh[16][HH];
  const int tid = threadIdx.x;
  const int r0 = blockIdx.x * 16;
  for (int u = tid; u < 16 * (HH / 4); u += 256) {
    int rr = u >> 6, c4 = (u & 63) * 4;
    *(float4*)&sh[rr][c4] = *(const float4*)(hid_all + (size_t)(r0 + rr) * HH + c4);
  }
  __syncthreads();
  for (int oi = tid; oi < 16 * NCLS; oi += 256) {
    int rr = oi / NCLS, cls = oi - rr * NCLS;
    const float* wg = W_gen + (size_t)cls * HH;
    float acc = 0.f;
#pragma unroll
    for (int k4 = 0; k4 < HH; k4 += 4) {
      float4 h4 = *(const float4*)&sh[rr][k4];
      float4 w4 = *(const float4*)(wg + k4);
      acc += h4.x * w4.x + h4.y * w4.y + h4.z * w4.z + h4.w * w4.w;
    }
    int r = r0 + rr;
    int s = r >> 11;
    int b = r & 2047;
    out[((size_t)b * NSTEP + s) * NCLS + cls] = acc + b_gen[cls];
  }
}

// ---------------------------------------------------------------------------
extern "C" void kernel_launch(void* const* d_in, const int* in_sizes, int n_in,
                              void* d_out, int out_size, void* d_ws, size_t ws_size,
                              hipStream_t stream) {
  const float* batch_H = (const float*)d_in[0];
  const int*   text    = (const int*)d_in[1];
  const float* W_i2h   = (const float*)d_in[2];
  const float* W_h2h   = (const float*)d_in[3];
  const float* b_h2h   = (const float*)d_in[4];
  const float* W_score = (const float*)d_in[5];
  const float* W_ih    = (const float*)d_in[6];
  const float* b_ih    = (const float*)d_in[7];
  const float* W_hh    = (const float*)d_in[8];
  const float* b_hh    = (const float*)d_in[9];
  const float* W_gen   = (const float*)d_in[10];
  const float* b_gen   = (const float*)d_in[11];
  float* out = (float*)d_out;

  // workspace layout (bytes)
  char* p = (char*)d_ws;
  unsigned short* bHbf = (unsigned short*)p;              p += (size_t)2048 * 32 * 512 * 2;  // 64 MiB
  unsigned short* Hbf  = (unsigned short*)p;              p += (size_t)65536 * 256 * 2;      // 32 MiB
  float* hiddens       = (float*)p;                       p += (size_t)27 * 2048 * 256 * 4;  // 54 MiB
  float* cbuf          = (float*)p;                       p += (size_t)2048 * 256 * 4;
  unsigned short* XSW  = (unsigned short*)p;              p += (size_t)2048 * (XCH * 32) * 2;
  unsigned short* Wg   = (unsigned short*)p;              p += (size_t)1024 * KTOT * 2;
  unsigned short* Wi   = (unsigned short*)p;              p += (size_t)256 * 512 * 2;
  float* WT            = (float*)p;                       p += (size_t)256 * 256 * 4;
  float* bc            = (float*)p;                       p += (size_t)1024 * 4;

  cvt_bh_kernel<<<16384, 256, 0, stream>>>(batch_H, bHbf);
  prep_wg_kernel<<<416, 256, 0, stream>>>(W_ih, W_hh, Wg);
  prep_wi_kernel<<<64, 256, 0, stream>>>(W_i2h, Wi);
  prep_wt_bc_kernel<<<256, 256, 0, stream>>>(W_h2h, b_ih, b_hh, WT, bc);
  init_zero_kernel<<<1280, 256, 0, stream>>>(hiddens, cbuf, XSW);

  hproj_mfma_kernel<<<512, 256, 0, stream>>>(bHbf, Wi, Hbf);

  for (int s = 0; s < NSTEP; ++s) {
    const float* h_s = hiddens + (size_t)s * 2048 * 256;
    float* h_next    = hiddens + (size_t)(s + 1) * 2048 * 256;
    attn_fused_kernel<<<256, 256, 0, stream>>>(Hbf, bHbf, h_s, WT, b_h2h, W_score,
                                               text, XSW, s);
    int hb_r = 18 + 8 * (s & 1);
    int hb_w = 18 + 8 * ((s + 1) & 1);
    lstm_mfma_kernel<<<dim3(4, 16), 256, 0, stream>>>(XSW, Wg, bc, cbuf, h_next,
                                                      XSW, hb_r, hb_w);
  }

  probs_kernel<<<3328, 256, 0, stream>>>(hiddens + (size_t)2048 * 256, W_gen, b_gen, out);
}

// Round 3
// 1675.079 us; speedup vs baseline: 3.7348x; 2.6245x over previous
//
#include <hip/hip_runtime.h>
#include <cstddef>

// Problem constants
#define TT    32       // T_ENC
#define DD    512      // D_IN
#define HH    256      // hidden
#define NCLS  38       // classes
#define NSTEP 26       // MAXLEN+1
#define KX    576      // padded x-part K (512 ctx + 38 onehot + 26 pad) = 18*32
#define KTOT  832      // KX + HH
#define NKC   26       // K chunks of 32 for gates GEMM
#define XCH   34       // XSW chunk count: 18 x-chunks + 8 h(even) + 8 h(odd)

typedef float f32x4 __attribute__((ext_vector_type(4)));
typedef short bf16x8 __attribute__((ext_vector_type(8)));

__device__ __forceinline__ float fast_tanh(float z) {
  float e = __expf(2.f * z);
  return 1.f - 2.f / (e + 1.f);
}
__device__ __forceinline__ float fast_sigmoid(float z) {
  return 1.f / (1.f + __expf(-z));
}
__device__ __forceinline__ float bf2f(unsigned short s) {
  union { unsigned int u; float f; } v; v.u = ((unsigned int)s) << 16; return v.f;
}
__device__ __forceinline__ unsigned short f2bf(float f) {  // RNE
  union { float ff; unsigned int u; } v; v.ff = f;
  unsigned int r = v.u + 0x7FFFu + ((v.u >> 16) & 1u);
  return (unsigned short)(r >> 16);
}
__device__ __forceinline__ unsigned int pk(unsigned short a, unsigned short b) {
  return (unsigned int)a | ((unsigned int)b << 16);
}

// ---------------------------------------------------------------------------
// batch_H fp32 -> bf16 row-major (33,554,432 elems; 8 per thread; grid 16384)
__global__ __launch_bounds__(256) void cvt_bh_kernel(const float* __restrict__ src,
                                                     unsigned short* __restrict__ dst) {
  int t = blockIdx.x * 256 + threadIdx.x;
  const float4* s4 = (const float4*)src + (size_t)t * 2;
  float4 a = s4[0], b = s4[1];
  uint4 o;
  o.x = pk(f2bf(a.x), f2bf(a.y));
  o.y = pk(f2bf(a.z), f2bf(a.w));
  o.z = pk(f2bf(b.x), f2bf(b.y));
  o.w = pk(f2bf(b.z), f2bf(b.w));
  ((uint4*)dst)[t] = o;
}

// gates weights: [W_ihP(576) | W_hh(256)] bf16, gate-interleaved cols, MFMA-B swizzled.
__global__ __launch_bounds__(256) void prep_wg_kernel(const float* __restrict__ W_ih,
                                                      const float* __restrict__ W_hh,
                                                      unsigned short* __restrict__ Wg) {
  int flat = blockIdx.x * 256 + threadIdx.x;   // 64*NKC*64 = 106496
  if (flat >= 64 * NKC * 64) return;
  int l = flat & 63, ntkc = flat >> 6;
  int nt = ntkc / NKC, kc = ntkc - nt * NKC;
  int col = nt * 16 + (l & 15);
  int gate = (col >> 6) & 3;
  int jg = (col >> 8) * 64 + (col & 63);
  int orig = gate * 256 + jg;
  int kbase = kc * 32 + (l >> 4) * 8;
  unsigned short e[8];
#pragma unroll
  for (int j = 0; j < 8; ++j) {
    int k = kbase + j;
    float v;
    if (k < DD + NCLS)      v = W_ih[orig * (DD + NCLS) + k];
    else if (k < KX)        v = 0.f;
    else                    v = W_hh[orig * HH + (k - KX)];
    e[j] = f2bf(v);
  }
  uint4 o = {pk(e[0], e[1]), pk(e[2], e[3]), pk(e[4], e[5]), pk(e[6], e[7])};
  ((uint4*)Wg)[flat] = o;
}

// W_i2h [256][512] -> bf16 MFMA-B swizzled [nt(16)][kc(16)][lane][8]
__global__ __launch_bounds__(256) void prep_wi_kernel(const float* __restrict__ W_i2h,
                                                      unsigned short* __restrict__ Wi) {
  int flat = blockIdx.x * 256 + threadIdx.x;   // 16*16*64 = 16384
  int l = flat & 63, ntkc = flat >> 6;
  int nt = ntkc >> 4, kc = ntkc & 15;
  int n = nt * 16 + (l & 15);
  int kbase = kc * 32 + (l >> 4) * 8;
  unsigned short e[8];
#pragma unroll
  for (int j = 0; j < 8; ++j) e[j] = f2bf(W_i2h[(size_t)n * DD + kbase + j]);
  uint4 o = {pk(e[0], e[1]), pk(e[2], e[3]), pk(e[4], e[5]), pk(e[6], e[7])};
  ((uint4*)Wi)[flat] = o;
}

// W_gen [38][256] -> bf16 MFMA-B swizzled [nt(3)][kc(8)][lane][8], cols padded to 48
__global__ __launch_bounds__(256) void prep_wgen_kernel(const float* __restrict__ W_gen,
                                                        unsigned short* __restrict__ Wgp) {
  int flat = blockIdx.x * 256 + threadIdx.x;   // 3*8*64 = 1536
  if (flat >= 1536) return;
  int l = flat & 63, ntkc = flat >> 6;
  int nt = ntkc >> 3, kc = ntkc & 7;
  int n = nt * 16 + (l & 15);
  int kbase = kc * 32 + (l >> 4) * 8;
  unsigned short e[8];
#pragma unroll
  for (int j = 0; j < 8; ++j)
    e[j] = (n < NCLS) ? f2bf(W_gen[(size_t)n * HH + kbase + j]) : (unsigned short)0;
  uint4 o = {pk(e[0], e[1]), pk(e[2], e[3]), pk(e[4], e[5]), pk(e[6], e[7])};
  ((uint4*)Wgp)[flat] = o;
}

// W_h2h transpose (fp32) + combined bias bc = b_ih + b_hh
__global__ __launch_bounds__(256) void prep_wt_bc_kernel(const float* __restrict__ W_h2h,
                                                         const float* __restrict__ b_ih,
                                                         const float* __restrict__ b_hh,
                                                         float* __restrict__ WT,
                                                         float* __restrict__ bc) {
  int flat = blockIdx.x * 256 + threadIdx.x;   // 65536
  int k = flat >> 8, c = flat & 255;
  WT[k * 256 + c] = W_h2h[c * 256 + k];
  if (flat < 1024) bc[flat] = b_ih[flat] + b_hh[flat];
}

// zero h0 (hiddens slot0), cbuf, XSW h-even chunks (18..25)
__global__ __launch_bounds__(256) void init_zero_kernel(float* __restrict__ hid0,
                                                        float* __restrict__ cbuf,
                                                        unsigned short* __restrict__ XSW) {
  int flat = blockIdx.x * 256 + threadIdx.x;   // 327680
  float4 z = {0.f, 0.f, 0.f, 0.f};
  if (flat < 131072) {
    ((float4*)hid0)[flat] = z;
  } else if (flat < 262144) {
    ((float4*)cbuf)[flat - 131072] = z;
  } else if (flat < 327680) {
    int j = flat - 262144;            // 128 mt * 8 kc * 64 lanes
    int mt = j >> 9, rem = j & 511;
    int kc = 18 + (rem >> 6), lane = rem & 63;
    uint4 zz = {0u, 0u, 0u, 0u};
    ((uint4*)XSW)[((size_t)mt * XCH + kc) * 64 + lane] = zz;
  }
}

// ---------------------------------------------------------------------------
// H_proj = batch_H(bf16) @ W_i2h^T -> bf16 [65536][256]; 512 blocks * 128 rows
__global__ __launch_bounds__(256) void hproj_mfma_kernel(const unsigned short* __restrict__ Abf,
                                                         const unsigned short* __restrict__ Wi,
                                                         unsigned short* __restrict__ Hbf) {
  const int tid = threadIdx.x;
  const int w = tid >> 6, l = tid & 63;
  const int li = l & 15, qd = l >> 4;
  const int m0 = blockIdx.x * 128 + w * 32;
  f32x4 acc[2][16];
#pragma unroll
  for (int a = 0; a < 2; ++a)
#pragma unroll
    for (int b = 0; b < 16; ++b) acc[a][b] = (f32x4){0.f, 0.f, 0.f, 0.f};
  const bf16x8* Wi8 = (const bf16x8*)Wi;
  for (int kc = 0; kc < 16; ++kc) {
    bf16x8 a0 = *(const bf16x8*)(Abf + (size_t)(m0 + li) * DD + kc * 32 + qd * 8);
    bf16x8 a1 = *(const bf16x8*)(Abf + (size_t)(m0 + 16 + li) * DD + kc * 32 + qd * 8);
#pragma unroll
    for (int nt = 0; nt < 16; ++nt) {
      bf16x8 b = Wi8[(nt * 16 + kc) * 64 + l];
      acc[0][nt] = __builtin_amdgcn_mfma_f32_16x16x32_bf16(a0, b, acc[0][nt], 0, 0, 0);
      acc[1][nt] = __builtin_amdgcn_mfma_f32_16x16x32_bf16(a1, b, acc[1][nt], 0, 0, 0);
    }
  }
#pragma unroll
  for (int mi = 0; mi < 2; ++mi)
#pragma unroll
    for (int nt = 0; nt < 16; ++nt)
#pragma unroll
      for (int r = 0; r < 4; ++r) {
        int row = m0 + mi * 16 + qd * 4 + r;
        Hbf[(size_t)row * HH + nt * 16 + li] = f2bf(acc[mi][nt][r]);
      }
}

// ---------------------------------------------------------------------------
// fused per-step: hp GEMV + attention + context; 512 blocks * 4 batch rows.
__global__ __launch_bounds__(256) void attn_fused_kernel(
    const unsigned short* __restrict__ Hbf, const unsigned short* __restrict__ bHbf,
    const float* __restrict__ h_s, const float* __restrict__ WT,
    const float* __restrict__ b_h2h, const float* __restrict__ W_score,
    const int* __restrict__ text, unsigned short* __restrict__ XSW, int s) {
  __shared__ float sh_h[4][HH];
  __shared__ float sh_hp[4][HH];
  __shared__ float sh_ws[HH];
  __shared__ float sh_e[4][TT];
  const int tid = threadIdx.x;
  const int b0 = blockIdx.x * 4;
  const int w = tid >> 6, ln = tid & 63;

  // load h rows (one float4 per thread) + W_score
  {
    int i = tid >> 6, c4 = (tid & 63) * 4;
    *(float4*)&sh_h[i][c4] = *(const float4*)(h_s + (size_t)(b0 + i) * HH + c4);
  }
  if (tid < HH / 4) ((float4*)sh_ws)[tid] = ((const float4*)W_score)[tid];
  __syncthreads();

  // hp[i][c] = sum_k h[i][k]*W_h2h[c][k] + b_h2h[c]; wave w owns row w, lane owns 4 cols
  {
    int i = w, c4 = ln * 4;
    float acc0 = 0.f, acc1 = 0.f, acc2 = 0.f, acc3 = 0.f;
#pragma unroll 4
    for (int k = 0; k < HH; ++k) {
      float a = sh_h[i][k];
      float4 wv = *(const float4*)(WT + k * 256 + c4);
      acc0 += a * wv.x; acc1 += a * wv.y; acc2 += a * wv.z; acc3 += a * wv.w;
    }
    float4 bb = *(const float4*)(b_h2h + c4);
    sh_hp[i][c4 + 0] = acc0 + bb.x; sh_hp[i][c4 + 1] = acc1 + bb.y;
    sh_hp[i][c4 + 2] = acc2 + bb.z; sh_hp[i][c4 + 3] = acc3 + bb.w;
  }
  __syncthreads();

  // e[i][t]: 8-lane groups; lane li8 covers j = c*64 + li8*8, c=0..3
  {
    const int sub = ln >> 3, li8 = ln & 7;
#pragma unroll
    for (int p = 0; p < 4; ++p) {
      int pi = p * 32 + w * 8 + sub;
      int i = pi >> 5, t = pi & 31;
      const unsigned short* hb = Hbf + ((size_t)(b0 + i) * TT + t) * HH;
      float v = 0.f;
#pragma unroll
      for (int c = 0; c < 4; ++c) {
        int j = c * 64 + li8 * 8;
        uint4 hv = *(const uint4*)(hb + j);
        float4 hp0 = *(const float4*)&sh_hp[i][j];
        float4 hp1 = *(const float4*)&sh_hp[i][j + 4];
        float4 ws0 = *(const float4*)&sh_ws[j];
        float4 ws1 = *(const float4*)&sh_ws[j + 4];
        v += fast_tanh(bf2f((unsigned short)(hv.x & 0xFFFF)) + hp0.x) * ws0.x;
        v += fast_tanh(bf2f((unsigned short)(hv.x >> 16))    + hp0.y) * ws0.y;
        v += fast_tanh(bf2f((unsigned short)(hv.y & 0xFFFF)) + hp0.z) * ws0.z;
        v += fast_tanh(bf2f((unsigned short)(hv.y >> 16))    + hp0.w) * ws0.w;
        v += fast_tanh(bf2f((unsigned short)(hv.z & 0xFFFF)) + hp1.x) * ws1.x;
        v += fast_tanh(bf2f((unsigned short)(hv.z >> 16))    + hp1.y) * ws1.y;
        v += fast_tanh(bf2f((unsigned short)(hv.w & 0xFFFF)) + hp1.z) * ws1.z;
        v += fast_tanh(bf2f((unsigned short)(hv.w >> 16))    + hp1.w) * ws1.w;
      }
      v += __shfl_xor(v, 1, 64);
      v += __shfl_xor(v, 2, 64);
      v += __shfl_xor(v, 4, 64);
      if (li8 == 0) sh_e[i][t] = v;
    }
  }
  __syncthreads();

  // softmax over t (32-lane groups = one row); threads 0..127
  if (tid < 128) {
    int i = tid >> 5, t = tid & 31;
    float e = sh_e[i][t];
    float mx = e;
#pragma unroll
    for (int m = 16; m >= 1; m >>= 1) mx = fmaxf(mx, __shfl_xor(mx, m, 32));
    float pexp = __expf(e - mx);
    float ssum = pexp;
#pragma unroll
    for (int m = 16; m >= 1; m >>= 1) ssum += __shfl_xor(ssum, m, 32);
    sh_e[i][t] = pexp / ssum;
  }
  __syncthreads();

  // context -> XSW chunks 0..15 (swizzled bf16); wave w owns row w, lane owns 8 d's
  {
    int i = w, d0 = ln * 8;
    int row = b0 + i;
    float acc[8] = {0.f, 0.f, 0.f, 0.f, 0.f, 0.f, 0.f, 0.f};
    const unsigned short* bh = bHbf + (size_t)row * TT * DD + d0;
#pragma unroll
    for (int t = 0; t < TT; ++t) {
      float a = sh_e[i][t];
      uint4 hv = *(const uint4*)(bh + (size_t)t * DD);
      acc[0] += a * bf2f((unsigned short)(hv.x & 0xFFFF));
      acc[1] += a * bf2f((unsigned short)(hv.x >> 16));
      acc[2] += a * bf2f((unsigned short)(hv.y & 0xFFFF));
      acc[3] += a * bf2f((unsigned short)(hv.y >> 16));
      acc[4] += a * bf2f((unsigned short)(hv.z & 0xFFFF));
      acc[5] += a * bf2f((unsigned short)(hv.z >> 16));
      acc[6] += a * bf2f((unsigned short)(hv.w & 0xFFFF));
      acc[7] += a * bf2f((unsigned short)(hv.w >> 16));
    }
    uint4 o = {pk(f2bf(acc[0]), f2bf(acc[1])), pk(f2bf(acc[2]), f2bf(acc[3])),
               pk(f2bf(acc[4]), f2bf(acc[5])), pk(f2bf(acc[6]), f2bf(acc[7]))};
    int lane_t = ((d0 & 31) >> 3) * 16 + (row & 15);
    ((uint4*)XSW)[((size_t)(row >> 4) * XCH + (d0 >> 5)) * 64 + lane_t] = o;
  }
  // onehot + zero pad -> XSW chunks 16..17
  if (tid < 32) {
    int i = tid >> 3, k0 = DD + (tid & 7) * 8;
    int row = b0 + i;
    int ch = text[row * NSTEP + s];
    unsigned short e8[8];
#pragma unroll
    for (int j = 0; j < 8; ++j) e8[j] = (k0 + j - DD == ch) ? (unsigned short)0x3F80 : (unsigned short)0;
    uint4 o = {pk(e8[0], e8[1]), pk(e8[2], e8[3]), pk(e8[4], e8[5]), pk(e8[6], e8[7])};
    int lane_t = ((k0 & 31) >> 3) * 16 + (row & 15);
    ((uint4*)XSW)[((size_t)(row >> 4) * XCH + (k0 >> 5)) * 64 + lane_t] = o;
  }
}

// ---------------------------------------------------------------------------
// gates MFMA + LSTM cell. grid (4 cg, 64 mg); block = 32 rows x 256 gate-cols.
// wave w owns jj=w: all 4 gates of unit slice jg = cg*64 + w*16 + li.
__global__ __launch_bounds__(256) void lstm_mfma_kernel(
    const unsigned short* __restrict__ XSW, const unsigned short* __restrict__ Wg,
    const float* __restrict__ bc, float* __restrict__ cbuf,
    float* __restrict__ hnext, unsigned short* __restrict__ hbf_out,
    unsigned short* __restrict__ XSWw, int hb_r, int hb_w) {
  const int tid = threadIdx.x;
  const int w = tid >> 6, l = tid & 63;
  const int li = l & 15, qd = l >> 4;
  const int cg = blockIdx.x;
  const int m0 = blockIdx.y * 32;
  const int mt0 = m0 >> 4;
  f32x4 acc[2][4];
#pragma unroll
  for (int a = 0; a < 2; ++a)
#pragma unroll
    for (int g = 0; g < 4; ++g) acc[a][g] = (f32x4){0.f, 0.f, 0.f, 0.f};
  const bf16x8* X8 = (const bf16x8*)XSW;
  const bf16x8* W8 = (const bf16x8*)Wg;
  for (int kc = 0; kc < NKC; ++kc) {
    int skc = (kc < 18) ? kc : (hb_r + (kc - 18));
    bf16x8 a0 = X8[((size_t)mt0 * XCH + skc) * 64 + l];
    bf16x8 a1 = X8[((size_t)(mt0 + 1) * XCH + skc) * 64 + l];
#pragma unroll
    for (int g = 0; g < 4; ++g) {
      bf16x8 b = W8[((size_t)(cg * 16 + g * 4 + w) * NKC + kc) * 64 + l];
      acc[0][g] = __builtin_amdgcn_mfma_f32_16x16x32_bf16(a0, b, acc[0][g], 0, 0, 0);
      acc[1][g] = __builtin_amdgcn_mfma_f32_16x16x32_bf16(a1, b, acc[1][g], 0, 0, 0);
    }
  }
  const int jg = cg * 64 + w * 16 + li;
  float bcv[4];
#pragma unroll
  for (int g = 0; g < 4; ++g) bcv[g] = bc[g * 256 + jg];
#pragma unroll
  for (int mi = 0; mi < 2; ++mi)
#pragma unroll
    for (int r = 0; r < 4; ++r) {
      int row = m0 + mi * 16 + qd * 4 + r;
      float iv = fast_sigmoid(acc[mi][0][r] + bcv[0]);
      float fv = fast_sigmoid(acc[mi][1][r] + bcv[1]);
      float gv = fast_tanh   (acc[mi][2][r] + bcv[2]);
      float ov = fast_sigmoid(acc[mi][3][r] + bcv[3]);
      float cold = cbuf[(size_t)row * HH + jg];
      float cn = fv * cold + iv * gv;
      float hn = ov * fast_tanh(cn);
      cbuf[(size_t)row * HH + jg] = cn;
      hnext[(size_t)row * HH + jg] = hn;
      hbf_out[(size_t)row * HH + jg] = f2bf(hn);
      int kcx = hb_w + (jg >> 5);
      int k2 = jg & 31;
      XSWw[((size_t)(row >> 4) * XCH + kcx) * 512 + ((k2 >> 3) * 16 + (row & 15)) * 8 + (k2 & 7)] = f2bf(hn);
    }
}

// ---------------------------------------------------------------------------
// probs via MFMA: rows r = s*2048+b of hidbf, N=48 (38 used). 416 blocks * 128 rows.
__global__ __launch_bounds__(256) void probs_mfma_kernel(
    const unsigned short* __restrict__ hidbf, const unsigned short* __restrict__ Wgp,
    const float* __restrict__ b_gen, float* __restrict__ out) {
  const int tid = threadIdx.x;
  const int w = tid >> 6, l = tid & 63;
  const int li = l & 15, qd = l >> 4;
  const int m0 = blockIdx.x * 128 + w * 32;
  f32x4 acc[2][3];
#pragma unroll
  for (int a = 0; a < 2; ++a)
#pragma unroll
    for (int n = 0; n < 3; ++n) acc[a][n] = (f32x4){0.f, 0.f, 0.f, 0.f};
  const bf16x8* W8 = (const bf16x8*)Wgp;
#pragma unroll
  for (int kc = 0; kc < 8; ++kc) {
    bf16x8 a0 = *(const bf16x8*)(hidbf + (size_t)(m0 + li) * HH + kc * 32 + qd * 8);
    bf16x8 a1 = *(const bf16x8*)(hidbf + (size_t)(m0 + 16 + li) * HH + kc * 32 + qd * 8);
#pragma unroll
    for (int nt = 0; nt < 3; ++nt) {
      bf16x8 b = W8[(nt * 8 + kc) * 64 + l];
      acc[0][nt] = __builtin_amdgcn_mfma_f32_16x16x32_bf16(a0, b, acc[0][nt], 0, 0, 0);
      acc[1][nt] = __builtin_amdgcn_mfma_f32_16x16x32_bf16(a1, b, acc[1][nt], 0, 0, 0);
    }
  }
  float bg[3];
#pragma unroll
  for (int nt = 0; nt < 3; ++nt) {
    int col = nt * 16 + li;
    bg[nt] = (col < NCLS) ? b_gen[col] : 0.f;
  }
#pragma unroll
  for (int mi = 0; mi < 2; ++mi)
#pragma unroll
    for (int nt = 0; nt < 3; ++nt) {
      int col = nt * 16 + li;
      if (col < NCLS) {
#pragma unroll
        for (int r = 0; r < 4; ++r) {
          int row = m0 + mi * 16 + qd * 4 + r;
          int s = row >> 11, b = row & 2047;
          out[((size_t)b * NSTEP + s) * NCLS + col] = acc[mi][nt][r] + bg[nt];
        }
      }
    }
}

// ---------------------------------------------------------------------------
extern "C" void kernel_launch(void* const* d_in, const int* in_sizes, int n_in,
                              void* d_out, int out_size, void* d_ws, size_t ws_size,
                              hipStream_t stream) {
  const float* batch_H = (const float*)d_in[0];
  const int*   text    = (const int*)d_in[1];
  const float* W_i2h   = (const float*)d_in[2];
  const float* W_h2h   = (const float*)d_in[3];
  const float* b_h2h   = (const float*)d_in[4];
  const float* W_score = (const float*)d_in[5];
  const float* W_ih    = (const float*)d_in[6];
  const float* b_ih    = (const float*)d_in[7];
  const float* W_hh    = (const float*)d_in[8];
  const float* b_hh    = (const float*)d_in[9];
  const float* W_gen   = (const float*)d_in[10];
  const float* b_gen   = (const float*)d_in[11];
  float* out = (float*)d_out;

  // workspace layout (bytes)
  char* p = (char*)d_ws;
  unsigned short* bHbf = (unsigned short*)p;              p += (size_t)2048 * 32 * 512 * 2;   // 64 MiB
  unsigned short* Hbf  = (unsigned short*)p;              p += (size_t)65536 * 256 * 2;       // 32 MiB
  float* hiddens       = (float*)p;                       p += (size_t)27 * 2048 * 256 * 4;   // 54 MiB
  unsigned short* hidbf= (unsigned short*)p;              p += (size_t)26 * 2048 * 256 * 2;   // 26 MiB
  float* cbuf          = (float*)p;                       p += (size_t)2048 * 256 * 4;
  unsigned short* XSW  = (unsigned short*)p;              p += (size_t)2048 * (XCH * 32) * 2;
  unsigned short* Wg   = (unsigned short*)p;              p += (size_t)1024 * KTOT * 2;
  unsigned short* Wi   = (unsigned short*)p;              p += (size_t)256 * 512 * 2;
  unsigned short* Wgp  = (unsigned short*)p;              p += (size_t)3 * 8 * 64 * 8 * 2;
  float* WT            = (float*)p;                       p += (size_t)256 * 256 * 4;
  float* bc            = (float*)p;                       p += (size_t)1024 * 4;

  cvt_bh_kernel<<<16384, 256, 0, stream>>>(batch_H, bHbf);
  prep_wg_kernel<<<416, 256, 0, stream>>>(W_ih, W_hh, Wg);
  prep_wi_kernel<<<64, 256, 0, stream>>>(W_i2h, Wi);
  prep_wgen_kernel<<<6, 256, 0, stream>>>(W_gen, Wgp);
  prep_wt_bc_kernel<<<256, 256, 0, stream>>>(W_h2h, b_ih, b_hh, WT, bc);
  init_zero_kernel<<<1280, 256, 0, stream>>>(hiddens, cbuf, XSW);

  hproj_mfma_kernel<<<512, 256, 0, stream>>>(bHbf, Wi, Hbf);

  for (int s = 0; s < NSTEP; ++s) {
    const float* h_s = hiddens + (size_t)s * 2048 * 256;
    float* h_next    = hiddens + (size_t)(s + 1) * 2048 * 256;
    unsigned short* hbf_s = hidbf + (size_t)s * 2048 * 256;
    attn_fused_kernel<<<512, 256, 0, stream>>>(Hbf, bHbf, h_s, WT, b_h2h, W_score,
                                               text, XSW, s);
    int hb_r = 18 + 8 * (s & 1);
    int hb_w = 18 + 8 * ((s + 1) & 1);
    lstm_mfma_kernel<<<dim3(4, 64), 256, 0, stream>>>(XSW, Wg, bc, cbuf, h_next,
                                                      hbf_s, XSW, hb_r, hb_w);
  }

  probs_mfma_kernel<<<416, 256, 0, stream>>>(hidbf, Wgp, b_gen, out);
}

// Round 4
// 1296.400 us; speedup vs baseline: 4.8258x; 1.2921x over previous
//
#include <hip/hip_runtime.h>
#include <cstddef>

// Problem constants
#define TT    32       // T_ENC
#define DD    512      // D_IN
#define HH    256      // hidden
#define NCLS  38       // classes
#define NSTEP 26       // MAXLEN+1
#define KX    576      // padded x-part K (512 ctx + 38 onehot + 26 pad) = 18*32
#define KTOT  832      // KX + HH
#define NKC   26       // K chunks of 32 for gates GEMM
#define XCH   34       // XSW chunk count: 18 x-chunks + 8 h(even) + 8 h(odd)

typedef float f32x4 __attribute__((ext_vector_type(4)));
typedef short bf16x8 __attribute__((ext_vector_type(8)));

__device__ __forceinline__ float fast_tanh(float z) {
  float e = __expf(2.f * z);
  return 1.f - 2.f / (e + 1.f);
}
__device__ __forceinline__ float fast_sigmoid(float z) {
  return 1.f / (1.f + __expf(-z));
}
__device__ __forceinline__ float bf2f(unsigned short s) {
  union { unsigned int u; float f; } v; v.u = ((unsigned int)s) << 16; return v.f;
}
__device__ __forceinline__ unsigned short f2bf(float f) {  // RNE
  union { float ff; unsigned int u; } v; v.ff = f;
  unsigned int r = v.u + 0x7FFFu + ((v.u >> 16) & 1u);
  return (unsigned short)(r >> 16);
}
__device__ __forceinline__ unsigned int pk(unsigned short a, unsigned short b) {
  return (unsigned int)a | ((unsigned int)b << 16);
}

// ---------------------------------------------------------------------------
// batch_H fp32 -> bf16 row-major (33,554,432 elems; 8 per thread; grid 16384)
__global__ __launch_bounds__(256) void cvt_bh_kernel(const float* __restrict__ src,
                                                     unsigned short* __restrict__ dst) {
  int t = blockIdx.x * 256 + threadIdx.x;
  const float4* s4 = (const float4*)src + (size_t)t * 2;
  float4 a = s4[0], b = s4[1];
  uint4 o;
  o.x = pk(f2bf(a.x), f2bf(a.y));
  o.y = pk(f2bf(a.z), f2bf(a.w));
  o.z = pk(f2bf(b.x), f2bf(b.y));
  o.w = pk(f2bf(b.z), f2bf(b.w));
  ((uint4*)dst)[t] = o;
}

// gates weights: [W_ihP(576) | W_hh(256)] bf16, gate-interleaved cols, MFMA-B swizzled.
__global__ __launch_bounds__(256) void prep_wg_kernel(const float* __restrict__ W_ih,
                                                      const float* __restrict__ W_hh,
                                                      unsigned short* __restrict__ Wg) {
  int flat = blockIdx.x * 256 + threadIdx.x;   // 64*NKC*64 = 106496
  if (flat >= 64 * NKC * 64) return;
  int l = flat & 63, ntkc = flat >> 6;
  int nt = ntkc / NKC, kc = ntkc - nt * NKC;
  int col = nt * 16 + (l & 15);
  int gate = (col >> 6) & 3;
  int jg = (col >> 8) * 64 + (col & 63);
  int orig = gate * 256 + jg;
  int kbase = kc * 32 + (l >> 4) * 8;
  unsigned short e[8];
#pragma unroll
  for (int j = 0; j < 8; ++j) {
    int k = kbase + j;
    float v;
    if (k < DD + NCLS)      v = W_ih[orig * (DD + NCLS) + k];
    else if (k < KX)        v = 0.f;
    else                    v = W_hh[orig * HH + (k - KX)];
    e[j] = f2bf(v);
  }
  uint4 o = {pk(e[0], e[1]), pk(e[2], e[3]), pk(e[4], e[5]), pk(e[6], e[7])};
  ((uint4*)Wg)[flat] = o;
}

// W_i2h [256][512] -> bf16 MFMA-B swizzled [nt(16)][kc(16)][lane][8]
__global__ __launch_bounds__(256) void prep_wi_kernel(const float* __restrict__ W_i2h,
                                                      unsigned short* __restrict__ Wi) {
  int flat = blockIdx.x * 256 + threadIdx.x;   // 16*16*64 = 16384
  int l = flat & 63, ntkc = flat >> 6;
  int nt = ntkc >> 4, kc = ntkc & 15;
  int n = nt * 16 + (l & 15);
  int kbase = kc * 32 + (l >> 4) * 8;
  unsigned short e[8];
#pragma unroll
  for (int j = 0; j < 8; ++j) e[j] = f2bf(W_i2h[(size_t)n * DD + kbase + j]);
  uint4 o = {pk(e[0], e[1]), pk(e[2], e[3]), pk(e[4], e[5]), pk(e[6], e[7])};
  ((uint4*)Wi)[flat] = o;
}

// W_gen [38][256] -> bf16 MFMA-B swizzled [nt(3)][kc(8)][lane][8], cols padded to 48
__global__ __launch_bounds__(256) void prep_wgen_kernel(const float* __restrict__ W_gen,
                                                        unsigned short* __restrict__ Wgp) {
  int flat = blockIdx.x * 256 + threadIdx.x;   // 3*8*64 = 1536
  if (flat >= 1536) return;
  int l = flat & 63, ntkc = flat >> 6;
  int nt = ntkc >> 3, kc = ntkc & 7;
  int n = nt * 16 + (l & 15);
  int kbase = kc * 32 + (l >> 4) * 8;
  unsigned short e[8];
#pragma unroll
  for (int j = 0; j < 8; ++j)
    e[j] = (n < NCLS) ? f2bf(W_gen[(size_t)n * HH + kbase + j]) : (unsigned short)0;
  uint4 o = {pk(e[0], e[1]), pk(e[2], e[3]), pk(e[4], e[5]), pk(e[6], e[7])};
  ((uint4*)Wgp)[flat] = o;
}

// W_h2h [256][256] -> bf16 MFMA-B swizzled [nt(16)][kc(8)][lane][8]; plus bc = b_ih+b_hh
__global__ __launch_bounds__(256) void prep_whb_bc_kernel(const float* __restrict__ W_h2h,
                                                          const float* __restrict__ b_ih,
                                                          const float* __restrict__ b_hh,
                                                          unsigned short* __restrict__ Whb,
                                                          float* __restrict__ bc) {
  int flat = blockIdx.x * 256 + threadIdx.x;   // 16*8*64 = 8192
  if (flat >= 8192) return;
  int l = flat & 63, ntkc = flat >> 6;
  int nt = ntkc >> 3, kc = ntkc & 7;
  int n = nt * 16 + (l & 15);
  int kbase = kc * 32 + (l >> 4) * 8;
  unsigned short e[8];
#pragma unroll
  for (int j = 0; j < 8; ++j) e[j] = f2bf(W_h2h[(size_t)n * HH + kbase + j]);
  uint4 o = {pk(e[0], e[1]), pk(e[2], e[3]), pk(e[4], e[5]), pk(e[6], e[7])};
  ((uint4*)Whb)[flat] = o;
  if (flat < 1024) bc[flat] = b_ih[flat] + b_hh[flat];
}

// zero cbuf + XSW h-even chunks (18..25)
__global__ __launch_bounds__(256) void init_zero_kernel(float* __restrict__ cbuf,
                                                        unsigned short* __restrict__ XSW) {
  int flat = blockIdx.x * 256 + threadIdx.x;   // 196608
  if (flat < 131072) {
    float4 z = {0.f, 0.f, 0.f, 0.f};
    ((float4*)cbuf)[flat] = z;
  } else {
    int j = flat - 131072;            // 128 mt * 8 kc * 64 lanes
    int mt = j >> 9, rem = j & 511;
    int kc = 18 + (rem >> 6), lane = rem & 63;
    uint4 zz = {0u, 0u, 0u, 0u};
    ((uint4*)XSW)[((size_t)mt * XCH + kc) * 64 + lane] = zz;
  }
}

// ---------------------------------------------------------------------------
// H_proj = batch_H(bf16) @ W_i2h^T -> bf16 [65536][256]; 512 blocks * 128 rows
__global__ __launch_bounds__(256) void hproj_mfma_kernel(const unsigned short* __restrict__ Abf,
                                                         const unsigned short* __restrict__ Wi,
                                                         unsigned short* __restrict__ Hbf) {
  const int tid = threadIdx.x;
  const int w = tid >> 6, l = tid & 63;
  const int li = l & 15, qd = l >> 4;
  const int m0 = blockIdx.x * 128 + w * 32;
  f32x4 acc[2][16];
#pragma unroll
  for (int a = 0; a < 2; ++a)
#pragma unroll
    for (int b = 0; b < 16; ++b) acc[a][b] = (f32x4){0.f, 0.f, 0.f, 0.f};
  const bf16x8* Wi8 = (const bf16x8*)Wi;
  for (int kc = 0; kc < 16; ++kc) {
    bf16x8 a0 = *(const bf16x8*)(Abf + (size_t)(m0 + li) * DD + kc * 32 + qd * 8);
    bf16x8 a1 = *(const bf16x8*)(Abf + (size_t)(m0 + 16 + li) * DD + kc * 32 + qd * 8);
#pragma unroll
    for (int nt = 0; nt < 16; ++nt) {
      bf16x8 b = Wi8[(nt * 16 + kc) * 64 + l];
      acc[0][nt] = __builtin_amdgcn_mfma_f32_16x16x32_bf16(a0, b, acc[0][nt], 0, 0, 0);
      acc[1][nt] = __builtin_amdgcn_mfma_f32_16x16x32_bf16(a1, b, acc[1][nt], 0, 0, 0);
    }
  }
#pragma unroll
  for (int mi = 0; mi < 2; ++mi)
#pragma unroll
    for (int nt = 0; nt < 16; ++nt)
#pragma unroll
      for (int r = 0; r < 4; ++r) {
        int row = m0 + mi * 16 + qd * 4 + r;
        Hbf[(size_t)row * HH + nt * 16 + li] = f2bf(acc[mi][nt][r]);
      }
}

// ---------------------------------------------------------------------------
// fused per-step: hp via MFMA (from XSW h-chunks + Whb) + attention + context.
// 512 blocks * 4 batch rows, 256 threads.
__global__ __launch_bounds__(256) void attn_fused_kernel(
    const unsigned short* __restrict__ Hbf, const unsigned short* __restrict__ bHbf,
    const unsigned short* __restrict__ XSWr, const unsigned short* __restrict__ Whb,
    const float* __restrict__ b_h2h, const float* __restrict__ W_score,
    const int* __restrict__ text, unsigned short* __restrict__ XSW, int s, int hb_r) {
  __shared__ float sh_hp[4][HH];
  __shared__ float sh_ws[HH];
  __shared__ float sh_e[4][TT];
  const int tid = threadIdx.x;
  const int b0 = blockIdx.x * 4;
  const int w = tid >> 6, ln = tid & 63;
  const int li = ln & 15, qd = ln >> 4;

  if (tid < HH / 4) ((float4*)sh_ws)[tid] = ((const float4*)W_score)[tid];

  // hp tile via MFMA: 16-row tile mt contains our 4 rows; wave w covers cols w*64..+63
  {
    const int mt = blockIdx.x >> 2;
    const int qsel = (b0 & 15) >> 2;
    f32x4 hacc[4];
#pragma unroll
    for (int n = 0; n < 4; ++n) hacc[n] = (f32x4){0.f, 0.f, 0.f, 0.f};
    const bf16x8* X8 = (const bf16x8*)XSWr;
    const bf16x8* WB = (const bf16x8*)Whb;
#pragma unroll
    for (int kc = 0; kc < 8; ++kc) {
      bf16x8 a = X8[((size_t)mt * XCH + hb_r + kc) * 64 + ln];
#pragma unroll
      for (int n = 0; n < 4; ++n) {
        bf16x8 b = WB[((w * 4 + n) * 8 + kc) * 64 + ln];
        hacc[n] = __builtin_amdgcn_mfma_f32_16x16x32_bf16(a, b, hacc[n], 0, 0, 0);
      }
    }
    if (qd == qsel) {
#pragma unroll
      for (int n = 0; n < 4; ++n) {
        int col = (w * 4 + n) * 16 + li;
        float bb = b_h2h[col];
#pragma unroll
        for (int r = 0; r < 4; ++r) sh_hp[r][col] = hacc[n][r] + bb;
      }
    }
  }
  __syncthreads();

  // e[i][t]: 8-lane groups; lane li8 covers j = c*64 + li8*8, c=0..3
  {
    const int sub = ln >> 3, li8 = ln & 7;
#pragma unroll
    for (int p = 0; p < 4; ++p) {
      int pi = p * 32 + w * 8 + sub;
      int i = pi >> 5, t = pi & 31;
      const unsigned short* hb = Hbf + ((size_t)(b0 + i) * TT + t) * HH;
      float v = 0.f;
#pragma unroll
      for (int c = 0; c < 4; ++c) {
        int j = c * 64 + li8 * 8;
        uint4 hv = *(const uint4*)(hb + j);
        float4 hp0 = *(const float4*)&sh_hp[i][j];
        float4 hp1 = *(const float4*)&sh_hp[i][j + 4];
        float4 ws0 = *(const float4*)&sh_ws[j];
        float4 ws1 = *(const float4*)&sh_ws[j + 4];
        v += fast_tanh(bf2f((unsigned short)(hv.x & 0xFFFF)) + hp0.x) * ws0.x;
        v += fast_tanh(bf2f((unsigned short)(hv.x >> 16))    + hp0.y) * ws0.y;
        v += fast_tanh(bf2f((unsigned short)(hv.y & 0xFFFF)) + hp0.z) * ws0.z;
        v += fast_tanh(bf2f((unsigned short)(hv.y >> 16))    + hp0.w) * ws0.w;
        v += fast_tanh(bf2f((unsigned short)(hv.z & 0xFFFF)) + hp1.x) * ws1.x;
        v += fast_tanh(bf2f((unsigned short)(hv.z >> 16))    + hp1.y) * ws1.y;
        v += fast_tanh(bf2f((unsigned short)(hv.w & 0xFFFF)) + hp1.z) * ws1.z;
        v += fast_tanh(bf2f((unsigned short)(hv.w >> 16))    + hp1.w) * ws1.w;
      }
      v += __shfl_xor(v, 1, 64);
      v += __shfl_xor(v, 2, 64);
      v += __shfl_xor(v, 4, 64);
      if (li8 == 0) sh_e[i][t] = v;
    }
  }
  __syncthreads();

  // softmax over t (32-lane groups = one row); threads 0..127
  if (tid < 128) {
    int i = tid >> 5, t = tid & 31;
    float e = sh_e[i][t];
    float mx = e;
#pragma unroll
    for (int m = 16; m >= 1; m >>= 1) mx = fmaxf(mx, __shfl_xor(mx, m, 32));
    float pexp = __expf(e - mx);
    float ssum = pexp;
#pragma unroll
    for (int m = 16; m >= 1; m >>= 1) ssum += __shfl_xor(ssum, m, 32);
    sh_e[i][t] = pexp / ssum;
  }
  __syncthreads();

  // context -> XSW chunks 0..15 (swizzled bf16); wave w owns row w, lane owns 8 d's
  {
    int i = w, d0 = ln * 8;
    int row = b0 + i;
    float acc[8] = {0.f, 0.f, 0.f, 0.f, 0.f, 0.f, 0.f, 0.f};
    const unsigned short* bh = bHbf + (size_t)row * TT * DD + d0;
#pragma unroll
    for (int t = 0; t < TT; ++t) {
      float a = sh_e[i][t];
      uint4 hv = *(const uint4*)(bh + (size_t)t * DD);
      acc[0] += a * bf2f((unsigned short)(hv.x & 0xFFFF));
      acc[1] += a * bf2f((unsigned short)(hv.x >> 16));
      acc[2] += a * bf2f((unsigned short)(hv.y & 0xFFFF));
      acc[3] += a * bf2f((unsigned short)(hv.y >> 16));
      acc[4] += a * bf2f((unsigned short)(hv.z & 0xFFFF));
      acc[5] += a * bf2f((unsigned short)(hv.z >> 16));
      acc[6] += a * bf2f((unsigned short)(hv.w & 0xFFFF));
      acc[7] += a * bf2f((unsigned short)(hv.w >> 16));
    }
    uint4 o = {pk(f2bf(acc[0]), f2bf(acc[1])), pk(f2bf(acc[2]), f2bf(acc[3])),
               pk(f2bf(acc[4]), f2bf(acc[5])), pk(f2bf(acc[6]), f2bf(acc[7]))};
    int lane_t = ((d0 & 31) >> 3) * 16 + (row & 15);
    ((uint4*)XSW)[((size_t)(row >> 4) * XCH + (d0 >> 5)) * 64 + lane_t] = o;
  }
  // onehot + zero pad -> XSW chunks 16..17
  if (tid < 32) {
    int i = tid >> 3, k0 = DD + (tid & 7) * 8;
    int row = b0 + i;
    int ch = text[row * NSTEP + s];
    unsigned short e8[8];
#pragma unroll
    for (int j = 0; j < 8; ++j) e8[j] = (k0 + j - DD == ch) ? (unsigned short)0x3F80 : (unsigned short)0;
    uint4 o = {pk(e8[0], e8[1]), pk(e8[2], e8[3]), pk(e8[4], e8[5]), pk(e8[6], e8[7])};
    int lane_t = ((k0 & 31) >> 3) * 16 + (row & 15);
    ((uint4*)XSW)[((size_t)(row >> 4) * XCH + (k0 >> 5)) * 64 + lane_t] = o;
  }
}

// ---------------------------------------------------------------------------
// gates MFMA + LSTM cell. grid (4 cg, 64 mg); block = 32 rows x 256 gate-cols.
__global__ __launch_bounds__(256) void lstm_mfma_kernel(
    const unsigned short* __restrict__ XSW, const unsigned short* __restrict__ Wg,
    const float* __restrict__ bc, float* __restrict__ cbuf,
    unsigned short* __restrict__ hbf_out, unsigned short* __restrict__ XSWw,
    int hb_r, int hb_w) {
  const int tid = threadIdx.x;
  const int w = tid >> 6, l = tid & 63;
  const int li = l & 15, qd = l >> 4;
  const int cg = blockIdx.x;
  const int m0 = blockIdx.y * 32;
  const int mt0 = m0 >> 4;
  f32x4 acc[2][4];
#pragma unroll
  for (int a = 0; a < 2; ++a)
#pragma unroll
    for (int g = 0; g < 4; ++g) acc[a][g] = (f32x4){0.f, 0.f, 0.f, 0.f};
  const bf16x8* X8 = (const bf16x8*)XSW;
  const bf16x8* W8 = (const bf16x8*)Wg;
  for (int kc = 0; kc < NKC; ++kc) {
    int skc = (kc < 18) ? kc : (hb_r + (kc - 18));
    bf16x8 a0 = X8[((size_t)mt0 * XCH + skc) * 64 + l];
    bf16x8 a1 = X8[((size_t)(mt0 + 1) * XCH + skc) * 64 + l];
#pragma unroll
    for (int g = 0; g < 4; ++g) {
      bf16x8 b = W8[((size_t)(cg * 16 + g * 4 + w) * NKC + kc) * 64 + l];
      acc[0][g] = __builtin_amdgcn_mfma_f32_16x16x32_bf16(a0, b, acc[0][g], 0, 0, 0);
      acc[1][g] = __builtin_amdgcn_mfma_f32_16x16x32_bf16(a1, b, acc[1][g], 0, 0, 0);
    }
  }
  const int jg = cg * 64 + w * 16 + li;
  float bcv[4];
#pragma unroll
  for (int g = 0; g < 4; ++g) bcv[g] = bc[g * 256 + jg];
#pragma unroll
  for (int mi = 0; mi < 2; ++mi)
#pragma unroll
    for (int r = 0; r < 4; ++r) {
      int row = m0 + mi * 16 + qd * 4 + r;
      float iv = fast_sigmoid(acc[mi][0][r] + bcv[0]);
      float fv = fast_sigmoid(acc[mi][1][r] + bcv[1]);
      float gv = fast_tanh   (acc[mi][2][r] + bcv[2]);
      float ov = fast_sigmoid(acc[mi][3][r] + bcv[3]);
      float cold = cbuf[(size_t)row * HH + jg];
      float cn = fv * cold + iv * gv;
      float hn = ov * fast_tanh(cn);
      cbuf[(size_t)row * HH + jg] = cn;
      unsigned short hb = f2bf(hn);
      hbf_out[(size_t)row * HH + jg] = hb;
      int kcx = hb_w + (jg >> 5);
      int k2 = jg & 31;
      XSWw[((size_t)(row >> 4) * XCH + kcx) * 512 + ((k2 >> 3) * 16 + (row & 15)) * 8 + (k2 & 7)] = hb;
    }
}

// ---------------------------------------------------------------------------
// probs via MFMA: rows r = s*2048+b of hidbf, N=48 (38 used). 416 blocks * 128 rows.
__global__ __launch_bounds__(256) void probs_mfma_kernel(
    const unsigned short* __restrict__ hidbf, const unsigned short* __restrict__ Wgp,
    const float* __restrict__ b_gen, float* __restrict__ out) {
  const int tid = threadIdx.x;
  const int w = tid >> 6, l = tid & 63;
  const int li = l & 15, qd = l >> 4;
  const int m0 = blockIdx.x * 128 + w * 32;
  f32x4 acc[2][3];
#pragma unroll
  for (int a = 0; a < 2; ++a)
#pragma unroll
    for (int n = 0; n < 3; ++n) acc[a][n] = (f32x4){0.f, 0.f, 0.f, 0.f};
  const bf16x8* W8 = (const bf16x8*)Wgp;
#pragma unroll
  for (int kc = 0; kc < 8; ++kc) {
    bf16x8 a0 = *(const bf16x8*)(hidbf + (size_t)(m0 + li) * HH + kc * 32 + qd * 8);
    bf16x8 a1 = *(const bf16x8*)(hidbf + (size_t)(m0 + 16 + li) * HH + kc * 32 + qd * 8);
#pragma unroll
    for (int nt = 0; nt < 3; ++nt) {
      bf16x8 b = W8[(nt * 8 + kc) * 64 + l];
      acc[0][nt] = __builtin_amdgcn_mfma_f32_16x16x32_bf16(a0, b, acc[0][nt], 0, 0, 0);
      acc[1][nt] = __builtin_amdgcn_mfma_f32_16x16x32_bf16(a1, b, acc[1][nt], 0, 0, 0);
    }
  }
  float bg[3];
#pragma unroll
  for (int nt = 0; nt < 3; ++nt) {
    int col = nt * 16 + li;
    bg[nt] = (col < NCLS) ? b_gen[col] : 0.f;
  }
#pragma unroll
  for (int mi = 0; mi < 2; ++mi)
#pragma unroll
    for (int nt = 0; nt < 3; ++nt) {
      int col = nt * 16 + li;
      if (col < NCLS) {
#pragma unroll
        for (int r = 0; r < 4; ++r) {
          int row = m0 + mi * 16 + qd * 4 + r;
          int s = row >> 11, b = row & 2047;
          out[((size_t)b * NSTEP + s) * NCLS + col] = acc[mi][nt][r] + bg[nt];
        }
      }
    }
}

// ---------------------------------------------------------------------------
extern "C" void kernel_launch(void* const* d_in, const int* in_sizes, int n_in,
                              void* d_out, int out_size, void* d_ws, size_t ws_size,
                              hipStream_t stream) {
  const float* batch_H = (const float*)d_in[0];
  const int*   text    = (const int*)d_in[1];
  const float* W_i2h   = (const float*)d_in[2];
  const float* W_h2h   = (const float*)d_in[3];
  const float* b_h2h   = (const float*)d_in[4];
  const float* W_score = (const float*)d_in[5];
  const float* W_ih    = (const float*)d_in[6];
  const float* b_ih    = (const float*)d_in[7];
  const float* W_hh    = (const float*)d_in[8];
  const float* b_hh    = (const float*)d_in[9];
  const float* W_gen   = (const float*)d_in[10];
  const float* b_gen   = (const float*)d_in[11];
  float* out = (float*)d_out;

  // workspace layout (bytes)
  char* p = (char*)d_ws;
  unsigned short* bHbf = (unsigned short*)p;              p += (size_t)2048 * 32 * 512 * 2;   // 64 MiB
  unsigned short* Hbf  = (unsigned short*)p;              p += (size_t)65536 * 256 * 2;       // 32 MiB
  unsigned short* hidbf= (unsigned short*)p;              p += (size_t)26 * 2048 * 256 * 2;   // 26 MiB
  float* cbuf          = (float*)p;                       p += (size_t)2048 * 256 * 4;
  unsigned short* XSW  = (unsigned short*)p;              p += (size_t)2048 * (XCH * 32) * 2;
  unsigned short* Wg   = (unsigned short*)p;              p += (size_t)1024 * KTOT * 2;
  unsigned short* Wi   = (unsigned short*)p;              p += (size_t)256 * 512 * 2;
  unsigned short* Wgp  = (unsigned short*)p;              p += (size_t)3 * 8 * 64 * 8 * 2;
  unsigned short* Whb  = (unsigned short*)p;              p += (size_t)16 * 8 * 64 * 8 * 2;
  float* bc            = (float*)p;                       p += (size_t)1024 * 4;

  cvt_bh_kernel<<<16384, 256, 0, stream>>>(batch_H, bHbf);
  prep_wg_kernel<<<416, 256, 0, stream>>>(W_ih, W_hh, Wg);
  prep_wi_kernel<<<64, 256, 0, stream>>>(W_i2h, Wi);
  prep_wgen_kernel<<<6, 256, 0, stream>>>(W_gen, Wgp);
  prep_whb_bc_kernel<<<32, 256, 0, stream>>>(W_h2h, b_ih, b_hh, Whb, bc);
  init_zero_kernel<<<768, 256, 0, stream>>>(cbuf, XSW);

  hproj_mfma_kernel<<<512, 256, 0, stream>>>(bHbf, Wi, Hbf);

  for (int s = 0; s < NSTEP; ++s) {
    unsigned short* hbf_s = hidbf + (size_t)s * 2048 * 256;
    int hb_r = 18 + 8 * (s & 1);
    int hb_w = 18 + 8 * ((s + 1) & 1);
    attn_fused_kernel<<<512, 256, 0, stream>>>(Hbf, bHbf, XSW, Whb, b_h2h, W_score,
                                               text, XSW, s, hb_r);
    lstm_mfma_kernel<<<dim3(4, 64), 256, 0, stream>>>(XSW, Wg, bc, cbuf,
                                                      hbf_s, XSW, hb_r, hb_w);
  }

  probs_mfma_kernel<<<416, 256, 0, stream>>>(hidbf, Wgp, b_gen, out);
}